// Round 3
// baseline (217.743 us; speedup 1.0000x reference)
//
#include <hip/hip_runtime.h>

typedef short v8s __attribute__((ext_vector_type(8)));
typedef float v4f __attribute__((ext_vector_type(4)));
typedef unsigned short u16;
typedef unsigned int u32;
typedef u16 v4u __attribute__((ext_vector_type(4)));

#define SS 4096
#define DD 256
#define QB 256
#define KVB 64

__device__ __forceinline__ u16 f2bf(float f) {
  u32 u = __builtin_bit_cast(u32, f);
  return (u16)((u + 0x7FFFu + ((u >> 16) & 1u)) >> 16);
}

__device__ __forceinline__ void gload16(const u16* g, u16* l) {
  __builtin_amdgcn_global_load_lds((const __attribute__((address_space(1))) u32*)g,
                                   (__attribute__((address_space(3))) u32*)l, 16, 0, 0);
}

// ---- transpose + cast weights: wt[p][n][k] = W_p[k][n] in bf16 ----
__global__ void wcast_kernel(const float* __restrict__ Wq, const float* __restrict__ Wk,
                             const float* __restrict__ Wv, u16* __restrict__ wt) {
  int f = blockIdx.x * 256 + threadIdx.x;   // 3*65536 total
  int p = f >> 16, rem = f & 65535, n = rem >> 8, k = rem & 255;
  const float* W = (p == 0) ? Wq : ((p == 1) ? Wk : Wv);
  wt[f] = f2bf(W[k * 256 + n]);
}

// ---- QKV projection (unchanged from round 2) ----
__global__ __launch_bounds__(256) void proj_kernel(
    const float* __restrict__ x, const u16* __restrict__ wt,
    const float* __restrict__ bq, const float* __restrict__ bk, const float* __restrict__ bv,
    u16* __restrict__ qg, u16* __restrict__ kg, u16* __restrict__ vtg) {
  __shared__ u16 xs[64 * 256];
  const int tid = threadIdx.x;
  const int lane = tid & 63, w = tid >> 6, g = lane >> 4, l15 = lane & 15;
  const int tok0 = blockIdx.x * 64;

#pragma unroll
  for (int it = 0; it < 8; ++it) {
    int idx = it * 256 + tid;
    int r = idx >> 5, d0 = (idx & 31) << 3;
    const float* src = x + (size_t)(tok0 + r) * DD + d0;
    float4 a = *(const float4*)src;
    float4 bb = *(const float4*)(src + 4);
    v8s pk;
    pk[0] = (short)f2bf(a.x);  pk[1] = (short)f2bf(a.y);
    pk[2] = (short)f2bf(a.z);  pk[3] = (short)f2bf(a.w);
    pk[4] = (short)f2bf(bb.x); pk[5] = (short)f2bf(bb.y);
    pk[6] = (short)f2bf(bb.z); pk[7] = (short)f2bf(bb.w);
    *(v8s*)(xs + r * DD + (((d0 >> 3) ^ (r & 7)) << 3)) = pk;
  }
  __syncthreads();

  v8s af[4][8];
#pragma unroll
  for (int m = 0; m < 4; ++m) {
    const int row = 16 * m + l15;
#pragma unroll
    for (int c = 0; c < 8; ++c)
      af[m][c] = *(const v8s*)(xs + row * DD + ((((4 * c + g) ^ (row & 7))) << 3));
  }

  const float SCL = 0.0625f * 1.44269504088896f;  // 1/sqrt(D) * log2(e)
  for (int p = 0; p < 3; ++p) {
    const u16* wbase = wt + p * 65536;
    const float* bias = (p == 0) ? bq : ((p == 1) ? bk : bv);
    v4f acc[4][4];
    const v4f vzero = {0.f, 0.f, 0.f, 0.f};
#pragma unroll
    for (int m = 0; m < 4; ++m)
#pragma unroll
      for (int t = 0; t < 4; ++t) acc[m][t] = vzero;
#pragma unroll
    for (int t = 0; t < 4; ++t) {
      const int n = 64 * w + 16 * t + l15;
      const u16* wrow = wbase + n * 256;
#pragma unroll
      for (int c = 0; c < 8; ++c) {
        v8s bf = *(const v8s*)(wrow + 8 * g + 32 * c);
#pragma unroll
        for (int m = 0; m < 4; ++m)
          acc[m][t] = __builtin_amdgcn_mfma_f32_16x16x32_bf16(af[m][c], bf, acc[m][t], 0, 0, 0);
      }
    }
    if (p == 0) {
#pragma unroll
      for (int t = 0; t < 4; ++t) {
        int n = 64 * w + 16 * t + l15;
        float bb = bias[n];
#pragma unroll
        for (int m = 0; m < 4; ++m)
#pragma unroll
          for (int r = 0; r < 4; ++r)
            qg[(size_t)(tok0 + 16 * m + 4 * g + r) * DD + n] = f2bf((acc[m][t][r] + bb) * SCL);
      }
    } else if (p == 1) {
#pragma unroll
      for (int t = 0; t < 4; ++t) {
        int n = 64 * w + 16 * t + l15;
        float bb = bias[n];
#pragma unroll
        for (int m = 0; m < 4; ++m)
#pragma unroll
          for (int r = 0; r < 4; ++r)
            kg[(size_t)(tok0 + 16 * m + 4 * g + r) * DD + n] = f2bf(acc[m][t][r] + bb);
      }
    } else {
      const int b = tok0 >> 12;
      const int s0 = tok0 & 4095;
#pragma unroll
      for (int t = 0; t < 4; ++t) {
        int n = 64 * w + 16 * t + l15;
        float bb = bias[n];
#pragma unroll
        for (int m = 0; m < 4; ++m) {
          v4u pk;
#pragma unroll
          for (int r = 0; r < 4; ++r) pk[r] = f2bf(acc[m][t][r] + bb);
          *(v4u*)(vtg + (size_t)(b * DD + n) * SS + s0 + 16 * m + 4 * g) = pk;
        }
      }
    }
  }
}

// ---- flash attention: 8 waves x 32 q-rows (QB=256), kv-split partials ----
#define STAGE(kt_, buf_)                                                         \
  {                                                                              \
    const int kt__ = (kt_); const int buf__ = (buf_);                            \
    _Pragma("unroll")                                                            \
    for (int it = 0; it < 4; ++it) {                                             \
      int idx = it * 512 + tid;                                                  \
      int r = idx >> 5, db = idx & 31;                                           \
      gload16(kbase + (size_t)(kt__ * 64 + r) * DD + ((db ^ (r & 7)) << 3),      \
              kb + buf__ * 16384 + idx * 8);                                     \
    }                                                                            \
    _Pragma("unroll")                                                            \
    for (int it = 0; it < 4; ++it) {                                             \
      int idx = it * 512 + tid;                                                  \
      int d = idx >> 3, jb = idx & 7;                                            \
      gload16(vbase + (size_t)d * SS + kt__ * 64 + ((jb ^ (d & 7)) << 3),        \
              vt + buf__ * 16384 + idx * 8);                                     \
    }                                                                            \
  }

__global__ __launch_bounds__(512, 2) void attn_kernel(
    const u16* __restrict__ qg, const u16* __restrict__ kg, const u16* __restrict__ vtg,
    float* __restrict__ o0, float* __restrict__ opart, float* __restrict__ ml,
    int nsplit, int nblk) {
  extern __shared__ u16 sm[];
  u16* kb = sm;                 // [2][64*256]   swizzled K tiles (also Q staging lo)
  u16* vt = sm + 32768;         // [2][256*64]   swizzled V^T tiles (Q staging hi)
  u16* pb = sm + 65536;         // [8][32*64]    per-wave P tiles

  const int bid = blockIdx.x;
  const int lg = (bid & 7) * (nblk >> 3) + (bid >> 3);  // XCD-contiguous logical id
  const int slice = lg >> 6;
  const int b = (lg >> 4) & 3;
  const int qt = lg & 15;
  const int NT = (SS / KVB) / nsplit;
  const int koff = slice * (SS / nsplit);

  const int tid = threadIdx.x;
  const int lane = tid & 63, w = tid >> 6, g = lane >> 4, l15 = lane & 15;

  const u16* qbase = qg + (size_t)(b * SS + qt * QB) * DD;
  const u16* kbase = kg + (size_t)(b * SS + koff) * DD;
  const u16* vbase = vtg + (size_t)b * DD * SS + koff;

  // stage Q tile (256x256 = 128 KB) into kb+vt, hoist Q B-fragments to registers
#pragma unroll
  for (int it = 0; it < 16; ++it) {
    int idx = it * 512 + tid;
    int r = idx >> 5, db = idx & 31;
    gload16(qbase + (size_t)r * DD + ((db ^ (r & 7)) << 3), sm + idx * 8);
  }
  __syncthreads();
  v8s qf[2][8];
#pragma unroll
  for (int j = 0; j < 2; ++j) {
    const int row = 32 * w + 16 * j + l15;
#pragma unroll
    for (int c = 0; c < 8; ++c)
      qf[j][c] = *(const v8s*)(sm + row * DD + ((((4 * c + g) ^ (row & 7))) << 3));
  }
  __syncthreads();

  float mrow[2], lrow[2];
  v4f oacc[2][16];
  const v4f vzero = {0.f, 0.f, 0.f, 0.f};
#pragma unroll
  for (int j = 0; j < 2; ++j) { mrow[j] = -1e30f; lrow[j] = 0.f; }
#pragma unroll
  for (int m = 0; m < 2; ++m)
#pragma unroll
    for (int t = 0; t < 16; ++t) oacc[m][t] = vzero;

  STAGE(0, 0);

  for (int kt = 0; kt < NT; ++kt) {
    const int cur = kt & 1;
    __syncthreads();                       // drains stage(kt); buf `cur` ready
    if (kt + 1 < NT) STAGE(kt + 1, cur ^ 1);
    const u16* kc = kb + cur * 16384;
    const u16* vc = vt + cur * 16384;

    // S^T = K @ Q^T : lane holds S[key=16t+4g+r][qrow=32w+16j+l15]
    v4f sacc[4][2];
#pragma unroll
    for (int t = 0; t < 4; ++t)
#pragma unroll
      for (int j = 0; j < 2; ++j) sacc[t][j] = vzero;
#pragma unroll
    for (int c = 0; c < 8; ++c) {
#pragma unroll
      for (int t = 0; t < 4; ++t) {
        const int krow = 16 * t + l15;
        v8s kf = *(const v8s*)(kc + krow * DD + ((((4 * c + g) ^ (krow & 7))) << 3));
#pragma unroll
        for (int j = 0; j < 2; ++j)
          sacc[t][j] = __builtin_amdgcn_mfma_f32_16x16x32_bf16(kf, qf[j][c], sacc[t][j], 0, 0, 0);
      }
    }

    // online softmax in log2 domain; per-qrow stats are l15-local (2 shuffles)
    float tm[2];
#pragma unroll
    for (int j = 0; j < 2; ++j) {
      float a0 = fmaxf(fmaxf(sacc[0][j][0], sacc[0][j][1]), fmaxf(sacc[0][j][2], sacc[0][j][3]));
      float a1 = fmaxf(fmaxf(sacc[1][j][0], sacc[1][j][1]), fmaxf(sacc[1][j][2], sacc[1][j][3]));
      float a2 = fmaxf(fmaxf(sacc[2][j][0], sacc[2][j][1]), fmaxf(sacc[2][j][2], sacc[2][j][3]));
      float a3 = fmaxf(fmaxf(sacc[3][j][0], sacc[3][j][1]), fmaxf(sacc[3][j][2], sacc[3][j][3]));
      float t0 = fmaxf(fmaxf(a0, a1), fmaxf(a2, a3));
      t0 = fmaxf(t0, __shfl_xor(t0, 16));
      t0 = fmaxf(t0, __shfl_xor(t0, 32));
      tm[j] = t0;
    }
    // defer-rescale (T13): skip O-pass when max growth <= 11 (log2 units)
    const bool need = !__all((tm[0] - mrow[0] <= 11.0f) && (tm[1] - mrow[1] <= 11.0f));
    if (need) {
      float sc[2];
#pragma unroll
      for (int j = 0; j < 2; ++j) {
        float nm = fmaxf(mrow[j], tm[j]);
        sc[j] = exp2f(mrow[j] - nm);
        mrow[j] = nm;
        lrow[j] *= sc[j];
      }
#pragma unroll
      for (int m = 0; m < 2; ++m) {
#pragma unroll
        for (int r = 0; r < 4; ++r) {
          float s4 = __shfl(sc[m], (lane & 48) | (4 * g + r));
#pragma unroll
          for (int t = 0; t < 16; ++t) oacc[m][t][r] *= s4;
        }
      }
    }

    // P = exp2(S - m): bf16 pack, b64 writes to per-wave LDS tile [32][64]
    u16* pw = pb + w * 2048;
#pragma unroll
    for (int j = 0; j < 2; ++j) {
      const int prow = 16 * j + l15;
      float ls = 0.f;
#pragma unroll
      for (int t = 0; t < 4; ++t) {
        v4u pk;
#pragma unroll
        for (int r = 0; r < 4; ++r) {
          float e = exp2f(sacc[t][j][r] - mrow[j]);
          ls += e;
          pk[r] = f2bf(e);
        }
        *(v4u*)(pw + prow * 64 + (((2 * t + (g >> 1)) ^ (prow & 7)) << 3) + 4 * (g & 1)) = pk;
      }
      ls += __shfl_xor(ls, 16);
      ls += __shfl_xor(ls, 32);
      lrow[j] += ls;
    }

    // O += P @ V  (A = P from per-wave LDS, B = V^T tile)
#pragma unroll
    for (int kc2 = 0; kc2 < 2; ++kc2) {
      v8s pa[2];
#pragma unroll
      for (int m = 0; m < 2; ++m) {
        const int row = 16 * m + l15;
        pa[m] = *(const v8s*)(pw + row * 64 + ((((4 * kc2 + g) ^ (row & 7))) << 3));
      }
#pragma unroll
      for (int t = 0; t < 16; ++t) {
        const int d = 16 * t + l15;
        v8s bvv = *(const v8s*)(vc + d * 64 + ((((4 * kc2 + g) ^ (d & 7))) << 3));
#pragma unroll
        for (int m = 0; m < 2; ++m)
          oacc[m][t] = __builtin_amdgcn_mfma_f32_16x16x32_bf16(pa[m], bvv, oacc[m][t], 0, 0, 0);
      }
    }
  }

  // epilogue: write UNNORMALIZED partial O (f32) + per-row (m, l)
  float* ob = (slice == 0) ? o0 : (opart + (size_t)(slice - 1) * 4194304);
  const size_t rb = (size_t)b * SS + (size_t)qt * QB;
  if (g == 0) {
#pragma unroll
    for (int j = 0; j < 2; ++j) {
      const size_t rowg = rb + 32 * w + 16 * j + l15;
      float2 v2 = make_float2(mrow[j], lrow[j]);
      *(float2*)(ml + ((size_t)slice * 16384 + rowg) * 2) = v2;
    }
  }
#pragma unroll
  for (int m = 0; m < 2; ++m)
#pragma unroll
    for (int t = 0; t < 16; ++t)
#pragma unroll
      for (int r = 0; r < 4; ++r)
        ob[(rb + 32 * w + 16 * m + 4 * g + r) * DD + 16 * t + l15] = oacc[m][t][r];
}

// ---- merge kv-split partials (normalize when nsplit==1) ----
__global__ __launch_bounds__(256) void combine_kernel(
    float* __restrict__ out, const float* __restrict__ opart,
    const float* __restrict__ ml, int nsplit) {
  const int tid = threadIdx.x;
  const size_t row = (size_t)blockIdx.x * 4 + (tid >> 6);
  const int d = (tid & 63) * 4;
  float2 mls[4];
  float mm = -1e30f;
#pragma unroll
  for (int s = 0; s < 4; ++s) {
    if (s < nsplit) {
      mls[s] = *(const float2*)(ml + ((size_t)s * 16384 + row) * 2);
      mm = fmaxf(mm, mls[s].x);
    }
  }
  float l = 0.f;
  float4 acc = {0.f, 0.f, 0.f, 0.f};
#pragma unroll
  for (int s = 0; s < 4; ++s) {
    if (s < nsplit) {
      float a = exp2f(mls[s].x - mm);
      const float* src = (s == 0) ? (out + row * DD + d)
                                  : (opart + (size_t)(s - 1) * 4194304 + row * DD + d);
      float4 v = *(const float4*)src;
      l += a * mls[s].y;
      acc.x += a * v.x; acc.y += a * v.y; acc.z += a * v.z; acc.w += a * v.w;
    }
  }
  float inv = 1.0f / l;
  acc.x *= inv; acc.y *= inv; acc.z *= inv; acc.w *= inv;
  *(float4*)(out + row * DD + d) = acc;
}

extern "C" void kernel_launch(void* const* d_in, const int* in_sizes, int n_in,
                              void* d_out, int out_size, void* d_ws, size_t ws_size,
                              hipStream_t stream) {
  const float* x  = (const float*)d_in[0];
  const float* Wq = (const float*)d_in[1];
  const float* bq = (const float*)d_in[2];
  const float* Wk = (const float*)d_in[3];
  const float* bk = (const float*)d_in[4];
  const float* Wv = (const float*)d_in[5];
  const float* bv = (const float*)d_in[6];
  float* out = (float*)d_out;
  char* ws = (char*)d_ws;

  u16* wt    = (u16*)ws;                                  //   393,216 B
  u16* qg    = (u16*)(ws + 393216);                       // 8,388,608 B
  u16* kg    = (u16*)(ws + 393216 + 8388608);             // 8,388,608 B
  u16* vtg   = (u16*)(ws + 393216 + 2 * 8388608);         // 8,388,608 B
  float* ml  = (float*)(ws + 25559040);                   //   524,288 B (4 slices)
  float* op  = (float*)(ws + 26083328);                   // up to 3 x 16,777,216 B
  const size_t need4 = 26083328ull + 3ull * 16777216ull;  // ~76.4 MB
  const size_t need2 = 26083328ull + 1ull * 16777216ull;  // ~42.9 MB
  const int nsplit = (ws_size >= need4) ? 4 : ((ws_size >= need2) ? 2 : 1);
  const int nblk = 64 * nsplit;

  (void)hipFuncSetAttribute((const void*)attn_kernel,
                            hipFuncAttributeMaxDynamicSharedMemorySize, 163840);

  wcast_kernel<<<dim3(768), dim3(256), 0, stream>>>(Wq, Wk, Wv, wt);
  proj_kernel<<<dim3(256), dim3(256), 0, stream>>>(x, wt, bq, bk, bv, qg, kg, vtg);
  attn_kernel<<<dim3(nblk), dim3(512), 163840, stream>>>(qg, kg, vtg, out, op, ml, nsplit, nblk);
  combine_kernel<<<dim3(4096), dim3(256), 0, stream>>>(out, op, ml, nsplit);
}

// Round 4
// 216.319 us; speedup vs baseline: 1.0066x; 1.0066x over previous
//
#include <hip/hip_runtime.h>

typedef short v8s __attribute__((ext_vector_type(8)));
typedef float v4f __attribute__((ext_vector_type(4)));
typedef unsigned short u16;
typedef unsigned int u32;
typedef u16 v4u __attribute__((ext_vector_type(4)));

#define SS 4096
#define DD 256
#define QB 256
#define KVB 64

__device__ __forceinline__ u16 f2bf(float f) {
  u32 u = __builtin_bit_cast(u32, f);
  return (u16)((u + 0x7FFFu + ((u >> 16) & 1u)) >> 16);
}

__device__ __forceinline__ void gload16(const u16* g, u16* l) {
  __builtin_amdgcn_global_load_lds((const __attribute__((address_space(1))) u32*)g,
                                   (__attribute__((address_space(3))) u32*)l, 16, 0, 0);
}

// ---- transpose + cast weights: wt[p][n][k] = W_p[k][n] in bf16 ----
__global__ void wcast_kernel(const float* __restrict__ Wq, const float* __restrict__ Wk,
                             const float* __restrict__ Wv, u16* __restrict__ wt) {
  int f = blockIdx.x * 256 + threadIdx.x;   // 3*65536 total
  int p = f >> 16, rem = f & 65535, n = rem >> 8, k = rem & 255;
  const float* W = (p == 0) ? Wq : ((p == 1) ? Wk : Wv);
  wt[f] = f2bf(W[k * 256 + n]);
}

// ---- QKV projection ----
__global__ __launch_bounds__(256) void proj_kernel(
    const float* __restrict__ x, const u16* __restrict__ wt,
    const float* __restrict__ bq, const float* __restrict__ bk, const float* __restrict__ bv,
    u16* __restrict__ qg, u16* __restrict__ kg, u16* __restrict__ vtg) {
  __shared__ u16 xs[64 * 256];
  const int tid = threadIdx.x;
  const int lane = tid & 63, w = tid >> 6, g = lane >> 4, l15 = lane & 15;
  const int tok0 = blockIdx.x * 64;

#pragma unroll
  for (int it = 0; it < 8; ++it) {
    int idx = it * 256 + tid;
    int r = idx >> 5, d0 = (idx & 31) << 3;
    const float* src = x + (size_t)(tok0 + r) * DD + d0;
    float4 a = *(const float4*)src;
    float4 bb = *(const float4*)(src + 4);
    v8s pk;
    pk[0] = (short)f2bf(a.x);  pk[1] = (short)f2bf(a.y);
    pk[2] = (short)f2bf(a.z);  pk[3] = (short)f2bf(a.w);
    pk[4] = (short)f2bf(bb.x); pk[5] = (short)f2bf(bb.y);
    pk[6] = (short)f2bf(bb.z); pk[7] = (short)f2bf(bb.w);
    *(v8s*)(xs + r * DD + (((d0 >> 3) ^ (r & 7)) << 3)) = pk;
  }
  __syncthreads();

  v8s af[4][8];
#pragma unroll
  for (int m = 0; m < 4; ++m) {
    const int row = 16 * m + l15;
#pragma unroll
    for (int c = 0; c < 8; ++c)
      af[m][c] = *(const v8s*)(xs + row * DD + ((((4 * c + g) ^ (row & 7))) << 3));
  }

  const float SCL = 0.0625f * 1.44269504088896f;  // 1/sqrt(D) * log2(e)
  for (int p = 0; p < 3; ++p) {
    const u16* wbase = wt + p * 65536;
    const float* bias = (p == 0) ? bq : ((p == 1) ? bk : bv);
    v4f acc[4][4];
    const v4f vzero = {0.f, 0.f, 0.f, 0.f};
#pragma unroll
    for (int m = 0; m < 4; ++m)
#pragma unroll
      for (int t = 0; t < 4; ++t) acc[m][t] = vzero;
#pragma unroll
    for (int t = 0; t < 4; ++t) {
      const int n = 64 * w + 16 * t + l15;
      const u16* wrow = wbase + n * 256;
#pragma unroll
      for (int c = 0; c < 8; ++c) {
        v8s bf = *(const v8s*)(wrow + 8 * g + 32 * c);
#pragma unroll
        for (int m = 0; m < 4; ++m)
          acc[m][t] = __builtin_amdgcn_mfma_f32_16x16x32_bf16(af[m][c], bf, acc[m][t], 0, 0, 0);
      }
    }
    if (p == 0) {
#pragma unroll
      for (int t = 0; t < 4; ++t) {
        int n = 64 * w + 16 * t + l15;
        float bb = bias[n];
#pragma unroll
        for (int m = 0; m < 4; ++m)
#pragma unroll
          for (int r = 0; r < 4; ++r)
            qg[(size_t)(tok0 + 16 * m + 4 * g + r) * DD + n] = f2bf((acc[m][t][r] + bb) * SCL);
      }
    } else if (p == 1) {
#pragma unroll
      for (int t = 0; t < 4; ++t) {
        int n = 64 * w + 16 * t + l15;
        float bb = bias[n];
#pragma unroll
        for (int m = 0; m < 4; ++m)
#pragma unroll
          for (int r = 0; r < 4; ++r)
            kg[(size_t)(tok0 + 16 * m + 4 * g + r) * DD + n] = f2bf(acc[m][t][r] + bb);
      }
    } else {
      const int b = tok0 >> 12;
      const int s0 = tok0 & 4095;
#pragma unroll
      for (int t = 0; t < 4; ++t) {
        int n = 64 * w + 16 * t + l15;
        float bb = bias[n];
#pragma unroll
        for (int m = 0; m < 4; ++m) {
          v4u pk;
#pragma unroll
          for (int r = 0; r < 4; ++r) pk[r] = f2bf(acc[m][t][r] + bb);
          *(v4u*)(vtg + (size_t)(b * DD + n) * SS + s0 + 16 * m + 4 * g) = pk;
        }
      }
    }
  }
}

// ---- flash attention: 8 waves x 32 q-rows (QB=256), kv-split partials ----
#define STAGE(kt_, buf_)                                                         \
  {                                                                              \
    const int kt__ = (kt_); const int buf__ = (buf_);                            \
    _Pragma("unroll")                                                            \
    for (int it = 0; it < 4; ++it) {                                             \
      int idx = it * 512 + tid;                                                  \
      int r = idx >> 5, db = idx & 31;                                           \
      gload16(kbase + (size_t)(kt__ * 64 + r) * DD + ((db ^ (r & 7)) << 3),      \
              kb + buf__ * 16384 + idx * 8);                                     \
    }                                                                            \
    _Pragma("unroll")                                                            \
    for (int it = 0; it < 4; ++it) {                                             \
      int idx = it * 512 + tid;                                                  \
      int d = idx >> 3, jb = idx & 7;                                            \
      gload16(vbase + (size_t)d * SS + kt__ * 64 + ((jb ^ (d & 7)) << 3),        \
              vt + buf__ * 16384 + idx * 8);                                     \
    }                                                                            \
  }

__global__ __launch_bounds__(512) void attn_kernel(
    const u16* __restrict__ qg, const u16* __restrict__ kg, const u16* __restrict__ vtg,
    float* __restrict__ o0, float* __restrict__ opart, float* __restrict__ ml,
    int nsplit, int nblk) {
  extern __shared__ u16 sm[];
  u16* kb = sm;                 // [2][64*256]   swizzled K tiles (also Q staging lo)
  u16* vt = sm + 32768;         // [2][256*64]   swizzled V^T tiles (Q staging hi)
  u16* pb = sm + 65536;         // [8][32*64]    per-wave P tiles

  const int bid = blockIdx.x;
  const int lg = (bid & 7) * (nblk >> 3) + (bid >> 3);  // XCD-contiguous logical id
  const int slice = lg >> 6;
  const int b = (lg >> 4) & 3;
  const int qt = lg & 15;
  const int NT = (SS / KVB) / nsplit;
  const int koff = slice * (SS / nsplit);

  const int tid = threadIdx.x;
  const int lane = tid & 63, w = tid >> 6, g = lane >> 4, l15 = lane & 15;

  const u16* qbase = qg + (size_t)(b * SS + qt * QB) * DD;
  const u16* kbase = kg + (size_t)(b * SS + koff) * DD;
  const u16* vbase = vtg + (size_t)b * DD * SS + koff;

  // stage Q tile (256x256 = 128 KB) into kb+vt, hoist Q B-fragments to registers
#pragma unroll
  for (int it = 0; it < 16; ++it) {
    int idx = it * 512 + tid;
    int r = idx >> 5, db = idx & 31;
    gload16(qbase + (size_t)r * DD + ((db ^ (r & 7)) << 3), sm + idx * 8);
  }
  __syncthreads();
  v8s qf[2][8];
#pragma unroll
  for (int j = 0; j < 2; ++j) {
    const int row = 32 * w + 16 * j + l15;
#pragma unroll
    for (int c = 0; c < 8; ++c)
      qf[j][c] = *(const v8s*)(sm + row * DD + ((((4 * c + g) ^ (row & 7))) << 3));
  }
  __syncthreads();

  float mrow[2], lrow[2];
  v4f oacc[2][16];
  const v4f vzero = {0.f, 0.f, 0.f, 0.f};
#pragma unroll
  for (int j = 0; j < 2; ++j) { mrow[j] = -1e30f; lrow[j] = 0.f; }
#pragma unroll
  for (int m = 0; m < 2; ++m)
#pragma unroll
    for (int t = 0; t < 16; ++t) oacc[m][t] = vzero;

  STAGE(0, 0);

  for (int kt = 0; kt < NT; ++kt) {
    const int cur = kt & 1;
    __syncthreads();                       // drains stage(kt); buf `cur` ready
    if (kt + 1 < NT) STAGE(kt + 1, cur ^ 1);
    const u16* kc = kb + cur * 16384;
    const u16* vc = vt + cur * 16384;

    // S^T = K @ Q^T : lane holds S[key=16t+4g+r][qrow=32w+16j+l15]
    v4f sacc[4][2];
#pragma unroll
    for (int t = 0; t < 4; ++t)
#pragma unroll
      for (int j = 0; j < 2; ++j) sacc[t][j] = vzero;
#pragma unroll
    for (int c = 0; c < 8; ++c) {
#pragma unroll
      for (int t = 0; t < 4; ++t) {
        const int krow = 16 * t + l15;
        v8s kf = *(const v8s*)(kc + krow * DD + ((((4 * c + g) ^ (krow & 7))) << 3));
#pragma unroll
        for (int j = 0; j < 2; ++j)
          sacc[t][j] = __builtin_amdgcn_mfma_f32_16x16x32_bf16(kf, qf[j][c], sacc[t][j], 0, 0, 0);
      }
    }

    // online softmax in log2 domain; per-qrow stats are l15-local (2 shuffles)
    float tm[2];
#pragma unroll
    for (int j = 0; j < 2; ++j) {
      float a0 = fmaxf(fmaxf(sacc[0][j][0], sacc[0][j][1]), fmaxf(sacc[0][j][2], sacc[0][j][3]));
      float a1 = fmaxf(fmaxf(sacc[1][j][0], sacc[1][j][1]), fmaxf(sacc[1][j][2], sacc[1][j][3]));
      float a2 = fmaxf(fmaxf(sacc[2][j][0], sacc[2][j][1]), fmaxf(sacc[2][j][2], sacc[2][j][3]));
      float a3 = fmaxf(fmaxf(sacc[3][j][0], sacc[3][j][1]), fmaxf(sacc[3][j][2], sacc[3][j][3]));
      float t0 = fmaxf(fmaxf(a0, a1), fmaxf(a2, a3));
      t0 = fmaxf(t0, __shfl_xor(t0, 16));
      t0 = fmaxf(t0, __shfl_xor(t0, 32));
      tm[j] = t0;
    }
    // defer-rescale (T13): skip O-pass when max growth <= 11 (log2 units)
    const bool need = !__all((tm[0] - mrow[0] <= 11.0f) && (tm[1] - mrow[1] <= 11.0f));
    if (need) {
      float sc[2];
#pragma unroll
      for (int j = 0; j < 2; ++j) {
        float nm = fmaxf(mrow[j], tm[j]);
        sc[j] = exp2f(mrow[j] - nm);
        mrow[j] = nm;
        lrow[j] *= sc[j];
      }
#pragma unroll
      for (int m = 0; m < 2; ++m) {
#pragma unroll
        for (int r = 0; r < 4; ++r) {
          float s4 = __shfl(sc[m], (lane & 48) | (4 * g + r));
#pragma unroll
          for (int t = 0; t < 16; ++t) oacc[m][t][r] *= s4;
        }
      }
    }

    // P = exp2(S - m): bf16 pack, b64 writes to per-wave LDS tile [32][64]
    u16* pw = pb + w * 2048;
#pragma unroll
    for (int j = 0; j < 2; ++j) {
      const int prow = 16 * j + l15;
      float ls = 0.f;
#pragma unroll
      for (int t = 0; t < 4; ++t) {
        v4u pk;
#pragma unroll
        for (int r = 0; r < 4; ++r) {
          float e = exp2f(sacc[t][j][r] - mrow[j]);
          ls += e;
          pk[r] = f2bf(e);
        }
        *(v4u*)(pw + prow * 64 + (((2 * t + (g >> 1)) ^ (prow & 7)) << 3) + 4 * (g & 1)) = pk;
      }
      ls += __shfl_xor(ls, 16);
      ls += __shfl_xor(ls, 32);
      lrow[j] += ls;
    }

    // O += P @ V  (A = P from per-wave LDS, B = V^T tile)
#pragma unroll
    for (int kc2 = 0; kc2 < 2; ++kc2) {
      v8s pa[2];
#pragma unroll
      for (int m = 0; m < 2; ++m) {
        const int row = 16 * m + l15;
        pa[m] = *(const v8s*)(pw + row * 64 + ((((4 * kc2 + g) ^ (row & 7))) << 3));
      }
#pragma unroll
      for (int t = 0; t < 16; ++t) {
        const int d = 16 * t + l15;
        v8s bvv = *(const v8s*)(vc + d * 64 + ((((4 * kc2 + g) ^ (d & 7))) << 3));
#pragma unroll
        for (int m = 0; m < 2; ++m)
          oacc[m][t] = __builtin_amdgcn_mfma_f32_16x16x32_bf16(pa[m], bvv, oacc[m][t], 0, 0, 0);
      }
    }
  }

  // epilogue: write UNNORMALIZED partial O (f32) + per-row (m, l)
  float* ob = (slice == 0) ? o0 : (opart + (size_t)(slice - 1) * 4194304);
  const size_t rb = (size_t)b * SS + (size_t)qt * QB;
  if (g == 0) {
#pragma unroll
    for (int j = 0; j < 2; ++j) {
      const size_t rowg = rb + 32 * w + 16 * j + l15;
      float2 v2 = make_float2(mrow[j], lrow[j]);
      *(float2*)(ml + ((size_t)slice * 16384 + rowg) * 2) = v2;
    }
  }
#pragma unroll
  for (int m = 0; m < 2; ++m)
#pragma unroll
    for (int t = 0; t < 16; ++t)
#pragma unroll
      for (int r = 0; r < 4; ++r)
        ob[(rb + 32 * w + 16 * m + 4 * g + r) * DD + 16 * t + l15] = oacc[m][t][r];
}

// ---- merge kv-split partials (normalize when nsplit==1) ----
__global__ __launch_bounds__(256) void combine_kernel(
    float* __restrict__ out, const float* __restrict__ opart,
    const float* __restrict__ ml, int nsplit) {
  const int tid = threadIdx.x;
  const size_t row = (size_t)blockIdx.x * 4 + (tid >> 6);
  const int d = (tid & 63) * 4;
  float2 mls[4];
  float mm = -1e30f;
#pragma unroll
  for (int s = 0; s < 4; ++s) {
    if (s < nsplit) {
      mls[s] = *(const float2*)(ml + ((size_t)s * 16384 + row) * 2);
      mm = fmaxf(mm, mls[s].x);
    }
  }
  float l = 0.f;
  float4 acc = {0.f, 0.f, 0.f, 0.f};
#pragma unroll
  for (int s = 0; s < 4; ++s) {
    if (s < nsplit) {
      float a = exp2f(mls[s].x - mm);
      const float* src = (s == 0) ? (out + row * DD + d)
                                  : (opart + (size_t)(s - 1) * 4194304 + row * DD + d);
      float4 v = *(const float4*)src;
      l += a * mls[s].y;
      acc.x += a * v.x; acc.y += a * v.y; acc.z += a * v.z; acc.w += a * v.w;
    }
  }
  float inv = 1.0f / l;
  acc.x *= inv; acc.y *= inv; acc.z *= inv; acc.w *= inv;
  *(float4*)(out + row * DD + d) = acc;
}

extern "C" void kernel_launch(void* const* d_in, const int* in_sizes, int n_in,
                              void* d_out, int out_size, void* d_ws, size_t ws_size,
                              hipStream_t stream) {
  const float* x  = (const float*)d_in[0];
  const float* Wq = (const float*)d_in[1];
  const float* bq = (const float*)d_in[2];
  const float* Wk = (const float*)d_in[3];
  const float* bk = (const float*)d_in[4];
  const float* Wv = (const float*)d_in[5];
  const float* bv = (const float*)d_in[6];
  float* out = (float*)d_out;
  char* ws = (char*)d_ws;

  u16* wt    = (u16*)ws;                                  //   393,216 B
  u16* qg    = (u16*)(ws + 393216);                       // 8,388,608 B
  u16* kg    = (u16*)(ws + 393216 + 8388608);             // 8,388,608 B
  u16* vtg   = (u16*)(ws + 393216 + 2 * 8388608);         // 8,388,608 B
  float* ml  = (float*)(ws + 25559040);                   //   524,288 B (4 slices)
  float* op  = (float*)(ws + 26083328);                   // up to 3 x 16,777,216 B
  const size_t need4 = 26083328ull + 3ull * 16777216ull;  // ~76.4 MB
  const size_t need2 = 26083328ull + 1ull * 16777216ull;  // ~42.9 MB
  const int nsplit = (ws_size >= need4) ? 4 : ((ws_size >= need2) ? 2 : 1);
  const int nblk = 64 * nsplit;

  (void)hipFuncSetAttribute((const void*)attn_kernel,
                            hipFuncAttributeMaxDynamicSharedMemorySize, 163840);

  wcast_kernel<<<dim3(768), dim3(256), 0, stream>>>(Wq, Wk, Wv, wt);
  proj_kernel<<<dim3(256), dim3(256), 0, stream>>>(x, wt, bq, bk, bv, qg, kg, vtg);
  attn_kernel<<<dim3(nblk), dim3(512), 163840, stream>>>(qg, kg, vtg, out, op, ml, nsplit, nblk);
  combine_kernel<<<dim3(4096), dim3(256), 0, stream>>>(out, op, ml, nsplit);
}

// Round 5
// 207.475 us; speedup vs baseline: 1.0495x; 1.0426x over previous
//
#include <hip/hip_runtime.h>

typedef short v8s __attribute__((ext_vector_type(8)));
typedef float v4f __attribute__((ext_vector_type(4)));
typedef unsigned short u16;
typedef unsigned int u32;
typedef u16 v4u __attribute__((ext_vector_type(4)));

#define SS 4096
#define DD 256
#define QB 256
#define KVB 64

__device__ __forceinline__ u16 f2bf(float f) {
  u32 u = __builtin_bit_cast(u32, f);
  return (u16)((u + 0x7FFFu + ((u >> 16) & 1u)) >> 16);
}

__device__ __forceinline__ void gload16(const u16* g, u16* l) {
  __builtin_amdgcn_global_load_lds((const __attribute__((address_space(1))) u32*)g,
                                   (__attribute__((address_space(3))) u32*)l, 16, 0, 0);
}

// ---- transpose + cast weights: wt[p][n][k] = W_p[k][n] in bf16 ----
__global__ void wcast_kernel(const float* __restrict__ Wq, const float* __restrict__ Wk,
                             const float* __restrict__ Wv, u16* __restrict__ wt) {
  int f = blockIdx.x * 256 + threadIdx.x;   // 3*65536 total
  int p = f >> 16, rem = f & 65535, n = rem >> 8, k = rem & 255;
  const float* W = (p == 0) ? Wq : ((p == 1) ? Wk : Wv);
  wt[f] = f2bf(W[k * 256 + n]);
}

// ---- QKV projection ----
__global__ __launch_bounds__(256) void proj_kernel(
    const float* __restrict__ x, const u16* __restrict__ wt,
    const float* __restrict__ bq, const float* __restrict__ bk, const float* __restrict__ bv,
    u16* __restrict__ qg, u16* __restrict__ kg, u16* __restrict__ vtg) {
  __shared__ u16 xs[64 * 256];
  const int tid = threadIdx.x;
  const int lane = tid & 63, w = tid >> 6, g = lane >> 4, l15 = lane & 15;
  const int tok0 = blockIdx.x * 64;

#pragma unroll
  for (int it = 0; it < 8; ++it) {
    int idx = it * 256 + tid;
    int r = idx >> 5, d0 = (idx & 31) << 3;
    const float* src = x + (size_t)(tok0 + r) * DD + d0;
    float4 a = *(const float4*)src;
    float4 bb = *(const float4*)(src + 4);
    v8s pk;
    pk[0] = (short)f2bf(a.x);  pk[1] = (short)f2bf(a.y);
    pk[2] = (short)f2bf(a.z);  pk[3] = (short)f2bf(a.w);
    pk[4] = (short)f2bf(bb.x); pk[5] = (short)f2bf(bb.y);
    pk[6] = (short)f2bf(bb.z); pk[7] = (short)f2bf(bb.w);
    *(v8s*)(xs + r * DD + (((d0 >> 3) ^ (r & 7)) << 3)) = pk;
  }
  __syncthreads();

  v8s af[4][8];
#pragma unroll
  for (int m = 0; m < 4; ++m) {
    const int row = 16 * m + l15;
#pragma unroll
    for (int c = 0; c < 8; ++c)
      af[m][c] = *(const v8s*)(xs + row * DD + ((((4 * c + g) ^ (row & 7))) << 3));
  }

  const float SCL = 0.0625f * 1.44269504088896f;  // 1/sqrt(D) * log2(e)
  for (int p = 0; p < 3; ++p) {
    const u16* wbase = wt + p * 65536;
    const float* bias = (p == 0) ? bq : ((p == 1) ? bk : bv);
    v4f acc[4][4];
    const v4f vzero = {0.f, 0.f, 0.f, 0.f};
#pragma unroll
    for (int m = 0; m < 4; ++m)
#pragma unroll
      for (int t = 0; t < 4; ++t) acc[m][t] = vzero;
#pragma unroll
    for (int t = 0; t < 4; ++t) {
      const int n = 64 * w + 16 * t + l15;
      const u16* wrow = wbase + n * 256;
#pragma unroll
      for (int c = 0; c < 8; ++c) {
        v8s bf = *(const v8s*)(wrow + 8 * g + 32 * c);
#pragma unroll
        for (int m = 0; m < 4; ++m)
          acc[m][t] = __builtin_amdgcn_mfma_f32_16x16x32_bf16(af[m][c], bf, acc[m][t], 0, 0, 0);
      }
    }
    if (p == 0) {
#pragma unroll
      for (int t = 0; t < 4; ++t) {
        int n = 64 * w + 16 * t + l15;
        float bb = bias[n];
#pragma unroll
        for (int m = 0; m < 4; ++m)
#pragma unroll
          for (int r = 0; r < 4; ++r)
            qg[(size_t)(tok0 + 16 * m + 4 * g + r) * DD + n] = f2bf((acc[m][t][r] + bb) * SCL);
      }
    } else if (p == 1) {
#pragma unroll
      for (int t = 0; t < 4; ++t) {
        int n = 64 * w + 16 * t + l15;
        float bb = bias[n];
#pragma unroll
        for (int m = 0; m < 4; ++m)
#pragma unroll
          for (int r = 0; r < 4; ++r)
            kg[(size_t)(tok0 + 16 * m + 4 * g + r) * DD + n] = f2bf(acc[m][t][r] + bb);
      }
    } else {
      const int b = tok0 >> 12;
      const int s0 = tok0 & 4095;
#pragma unroll
      for (int t = 0; t < 4; ++t) {
        int n = 64 * w + 16 * t + l15;
        float bb = bias[n];
#pragma unroll
        for (int m = 0; m < 4; ++m) {
          v4u pk;
#pragma unroll
          for (int r = 0; r < 4; ++r) pk[r] = f2bf(acc[m][t][r] + bb);
          *(v4u*)(vtg + (size_t)(b * DD + n) * SS + s0 + 16 * m + 4 * g) = pk;
        }
      }
    }
  }
}

// ---- flash attention: 8 waves x 32 q-rows (QB=256), kv-split partials ----
#define STAGE(kt_, buf_)                                                         \
  {                                                                              \
    const int kt__ = (kt_); const int buf__ = (buf_);                            \
    _Pragma("unroll")                                                            \
    for (int it = 0; it < 4; ++it) {                                             \
      int idx = it * 512 + tid;                                                  \
      int r = idx >> 5, db = idx & 31;                                           \
      gload16(kbase + (size_t)(kt__ * 64 + r) * DD + ((db ^ (r & 7)) << 3),      \
              kb + buf__ * 16384 + idx * 8);                                     \
    }                                                                            \
    _Pragma("unroll")                                                            \
    for (int it = 0; it < 4; ++it) {                                             \
      int idx = it * 512 + tid;                                                  \
      int d = idx >> 3, jb = idx & 7;                                            \
      gload16(vbase + (size_t)d * SS + kt__ * 64 + ((jb ^ (d & 7)) << 3),        \
              vt + buf__ * 16384 + idx * 8);                                     \
    }                                                                            \
  }

__global__ __attribute__((amdgpu_flat_work_group_size(512, 512),
                          amdgpu_waves_per_eu(2, 2))) void attn_kernel(
    const u16* __restrict__ qg, const u16* __restrict__ kg, const u16* __restrict__ vtg,
    float* __restrict__ o0, float* __restrict__ opart, float* __restrict__ ml,
    int nsplit, int nblk) {
  extern __shared__ u16 sm[];
  u16* kb = sm;                 // [2][64*256]   swizzled K tiles (also Q staging lo)
  u16* vt = sm + 32768;         // [2][256*64]   swizzled V^T tiles (Q staging hi)
  u16* pb = sm + 65536;         // [8][32*64]    per-wave P tiles

  const int bid = blockIdx.x;
  const int lg = (bid & 7) * (nblk >> 3) + (bid >> 3);  // XCD-contiguous logical id
  const int slice = lg >> 6;
  const int b = (lg >> 4) & 3;
  const int qt = lg & 15;
  const int NT = (SS / KVB) / nsplit;
  const int koff = slice * (SS / nsplit);

  const int tid = threadIdx.x;
  const int lane = tid & 63, w = tid >> 6, g = lane >> 4, l15 = lane & 15;

  const u16* qbase = qg + (size_t)(b * SS + qt * QB) * DD;
  const u16* kbase = kg + (size_t)(b * SS + koff) * DD;
  const u16* vbase = vtg + (size_t)b * DD * SS + koff;

  // stage Q tile (256x256 = 128 KB) into kb+vt, hoist Q B-fragments to registers
#pragma unroll
  for (int it = 0; it < 16; ++it) {
    int idx = it * 512 + tid;
    int r = idx >> 5, db = idx & 31;
    gload16(qbase + (size_t)r * DD + ((db ^ (r & 7)) << 3), sm + idx * 8);
  }
  __syncthreads();
  v8s qf[2][8];
#pragma unroll
  for (int j = 0; j < 2; ++j) {
    const int row = 32 * w + 16 * j + l15;
#pragma unroll
    for (int c = 0; c < 8; ++c)
      qf[j][c] = *(const v8s*)(sm + row * DD + ((((4 * c + g) ^ (row & 7))) << 3));
  }
  __syncthreads();

  float mrow[2], lrow[2];
  v4f oacc[2][16];
  const v4f vzero = {0.f, 0.f, 0.f, 0.f};
#pragma unroll
  for (int j = 0; j < 2; ++j) { mrow[j] = -1e30f; lrow[j] = 0.f; }
#pragma unroll
  for (int m = 0; m < 2; ++m)
#pragma unroll
    for (int t = 0; t < 16; ++t) oacc[m][t] = vzero;

  STAGE(0, 0);

  for (int kt = 0; kt < NT; ++kt) {
    const int cur = kt & 1;
    __syncthreads();                       // drains stage(kt); buf `cur` ready
    if (kt + 1 < NT) STAGE(kt + 1, cur ^ 1);
    const u16* kc = kb + cur * 16384;
    const u16* vc = vt + cur * 16384;

    // S^T = K @ Q^T : lane holds S[key=16t+4g+r][qrow=32w+16j+l15]
    v4f sacc[4][2];
#pragma unroll
    for (int t = 0; t < 4; ++t)
#pragma unroll
      for (int j = 0; j < 2; ++j) sacc[t][j] = vzero;
#pragma unroll
    for (int c = 0; c < 8; ++c) {
#pragma unroll
      for (int t = 0; t < 4; ++t) {
        const int krow = 16 * t + l15;
        v8s kf = *(const v8s*)(kc + krow * DD + ((((4 * c + g) ^ (krow & 7))) << 3));
#pragma unroll
        for (int j = 0; j < 2; ++j)
          sacc[t][j] = __builtin_amdgcn_mfma_f32_16x16x32_bf16(kf, qf[j][c], sacc[t][j], 0, 0, 0);
      }
    }

    // online softmax in log2 domain; per-qrow stats are l15-local (2 shuffles)
    float tm[2];
#pragma unroll
    for (int j = 0; j < 2; ++j) {
      float a0 = fmaxf(fmaxf(sacc[0][j][0], sacc[0][j][1]), fmaxf(sacc[0][j][2], sacc[0][j][3]));
      float a1 = fmaxf(fmaxf(sacc[1][j][0], sacc[1][j][1]), fmaxf(sacc[1][j][2], sacc[1][j][3]));
      float a2 = fmaxf(fmaxf(sacc[2][j][0], sacc[2][j][1]), fmaxf(sacc[2][j][2], sacc[2][j][3]));
      float a3 = fmaxf(fmaxf(sacc[3][j][0], sacc[3][j][1]), fmaxf(sacc[3][j][2], sacc[3][j][3]));
      float t0 = fmaxf(fmaxf(a0, a1), fmaxf(a2, a3));
      t0 = fmaxf(t0, __shfl_xor(t0, 16));
      t0 = fmaxf(t0, __shfl_xor(t0, 32));
      tm[j] = t0;
    }
    // defer-rescale (T13): skip O-pass when max growth <= 11 (log2 units)
    const bool need = !__all((tm[0] - mrow[0] <= 11.0f) && (tm[1] - mrow[1] <= 11.0f));
    if (need) {
      float sc[2];
#pragma unroll
      for (int j = 0; j < 2; ++j) {
        float nm = fmaxf(mrow[j], tm[j]);
        sc[j] = exp2f(mrow[j] - nm);
        mrow[j] = nm;
        lrow[j] *= sc[j];
      }
#pragma unroll
      for (int m = 0; m < 2; ++m) {
#pragma unroll
        for (int r = 0; r < 4; ++r) {
          float s4 = __shfl(sc[m], (lane & 48) | (4 * g + r));
#pragma unroll
          for (int t = 0; t < 16; ++t) oacc[m][t][r] *= s4;
        }
      }
    }

    // P = exp2(S - m): bf16 pack, b64 writes to per-wave LDS tile [32][64]
    u16* pw = pb + w * 2048;
#pragma unroll
    for (int j = 0; j < 2; ++j) {
      const int prow = 16 * j + l15;
      float ls = 0.f;
#pragma unroll
      for (int t = 0; t < 4; ++t) {
        v4u pk;
#pragma unroll
        for (int r = 0; r < 4; ++r) {
          float e = exp2f(sacc[t][j][r] - mrow[j]);
          ls += e;
          pk[r] = f2bf(e);
        }
        *(v4u*)(pw + prow * 64 + (((2 * t + (g >> 1)) ^ (prow & 7)) << 3) + 4 * (g & 1)) = pk;
      }
      ls += __shfl_xor(ls, 16);
      ls += __shfl_xor(ls, 32);
      lrow[j] += ls;
    }

    // O += P @ V  (A = P from per-wave LDS, B = V^T tile)
#pragma unroll
    for (int kc2 = 0; kc2 < 2; ++kc2) {
      v8s pa[2];
#pragma unroll
      for (int m = 0; m < 2; ++m) {
        const int row = 16 * m + l15;
        pa[m] = *(const v8s*)(pw + row * 64 + ((((4 * kc2 + g) ^ (row & 7))) << 3));
      }
#pragma unroll
      for (int t = 0; t < 16; ++t) {
        const int d = 16 * t + l15;
        v8s bvv = *(const v8s*)(vc + d * 64 + ((((4 * kc2 + g) ^ (d & 7))) << 3));
#pragma unroll
        for (int m = 0; m < 2; ++m)
          oacc[m][t] = __builtin_amdgcn_mfma_f32_16x16x32_bf16(pa[m], bvv, oacc[m][t], 0, 0, 0);
      }
    }
  }

  // epilogue: write UNNORMALIZED partial O (f32) + per-row (m, l)
  float* ob = (slice == 0) ? o0 : (opart + (size_t)(slice - 1) * 4194304);
  const size_t rb = (size_t)b * SS + (size_t)qt * QB;
  if (g == 0) {
#pragma unroll
    for (int j = 0; j < 2; ++j) {
      const size_t rowg = rb + 32 * w + 16 * j + l15;
      float2 v2 = make_float2(mrow[j], lrow[j]);
      *(float2*)(ml + ((size_t)slice * 16384 + rowg) * 2) = v2;
    }
  }
#pragma unroll
  for (int m = 0; m < 2; ++m)
#pragma unroll
    for (int t = 0; t < 16; ++t)
#pragma unroll
      for (int r = 0; r < 4; ++r)
        ob[(rb + 32 * w + 16 * m + 4 * g + r) * DD + 16 * t + l15] = oacc[m][t][r];
}

// ---- merge kv-split partials (normalize when nsplit==1) ----
__global__ __launch_bounds__(256) void combine_kernel(
    float* __restrict__ out, const float* __restrict__ opart,
    const float* __restrict__ ml, int nsplit) {
  const int tid = threadIdx.x;
  const size_t row = (size_t)blockIdx.x * 4 + (tid >> 6);
  const int d = (tid & 63) * 4;
  float2 mls[4];
  float mm = -1e30f;
#pragma unroll
  for (int s = 0; s < 4; ++s) {
    if (s < nsplit) {
      mls[s] = *(const float2*)(ml + ((size_t)s * 16384 + row) * 2);
      mm = fmaxf(mm, mls[s].x);
    }
  }
  float l = 0.f;
  float4 acc = {0.f, 0.f, 0.f, 0.f};
#pragma unroll
  for (int s = 0; s < 4; ++s) {
    if (s < nsplit) {
      float a = exp2f(mls[s].x - mm);
      const float* src = (s == 0) ? (out + row * DD + d)
                                  : (opart + (size_t)(s - 1) * 4194304 + row * DD + d);
      float4 v = *(const float4*)src;
      l += a * mls[s].y;
      acc.x += a * v.x; acc.y += a * v.y; acc.z += a * v.z; acc.w += a * v.w;
    }
  }
  float inv = 1.0f / l;
  acc.x *= inv; acc.y *= inv; acc.z *= inv; acc.w *= inv;
  *(float4*)(out + row * DD + d) = acc;
}

extern "C" void kernel_launch(void* const* d_in, const int* in_sizes, int n_in,
                              void* d_out, int out_size, void* d_ws, size_t ws_size,
                              hipStream_t stream) {
  const float* x  = (const float*)d_in[0];
  const float* Wq = (const float*)d_in[1];
  const float* bq = (const float*)d_in[2];
  const float* Wk = (const float*)d_in[3];
  const float* bk = (const float*)d_in[4];
  const float* Wv = (const float*)d_in[5];
  const float* bv = (const float*)d_in[6];
  float* out = (float*)d_out;
  char* ws = (char*)d_ws;

  u16* wt    = (u16*)ws;                                  //   393,216 B
  u16* qg    = (u16*)(ws + 393216);                       // 8,388,608 B
  u16* kg    = (u16*)(ws + 393216 + 8388608);             // 8,388,608 B
  u16* vtg   = (u16*)(ws + 393216 + 2 * 8388608);         // 8,388,608 B
  float* ml  = (float*)(ws + 25559040);                   //   524,288 B (4 slices)
  float* op  = (float*)(ws + 26083328);                   // up to 3 x 16,777,216 B
  const size_t need4 = 26083328ull + 3ull * 16777216ull;  // ~76.4 MB
  const size_t need2 = 26083328ull + 1ull * 16777216ull;  // ~42.9 MB
  const int nsplit = (ws_size >= need4) ? 4 : ((ws_size >= need2) ? 2 : 1);
  const int nblk = 64 * nsplit;

  (void)hipFuncSetAttribute((const void*)attn_kernel,
                            hipFuncAttributeMaxDynamicSharedMemorySize, 163840);

  wcast_kernel<<<dim3(768), dim3(256), 0, stream>>>(Wq, Wk, Wv, wt);
  proj_kernel<<<dim3(256), dim3(256), 0, stream>>>(x, wt, bq, bk, bv, qg, kg, vtg);
  attn_kernel<<<dim3(nblk), dim3(512), 163840, stream>>>(qg, kg, vtg, out, op, ml, nsplit, nblk);
  combine_kernel<<<dim3(4096), dim3(256), 0, stream>>>(out, op, ml, nsplit);
}

// Round 6
// 185.897 us; speedup vs baseline: 1.1713x; 1.1161x over previous
//
#include <hip/hip_runtime.h>

typedef short v8s __attribute__((ext_vector_type(8)));
typedef float v4f __attribute__((ext_vector_type(4)));
typedef unsigned short u16;
typedef unsigned int u32;
typedef u16 v4u __attribute__((ext_vector_type(4)));

#define SS 4096
#define DD 256
#define QB 128
#define KVB 64

__device__ __forceinline__ u16 f2bf(float f) {
  u32 u = __builtin_bit_cast(u32, f);
  return (u16)((u + 0x7FFFu + ((u >> 16) & 1u)) >> 16);
}

__device__ __forceinline__ void gload16(const u16* g, u16* l) {
  __builtin_amdgcn_global_load_lds((const __attribute__((address_space(1))) u32*)g,
                                   (__attribute__((address_space(3))) u32*)l, 16, 0, 0);
}

// ---- transpose + cast weights: wt[p][n][k] = W_p[k][n] in bf16 ----
__global__ void wcast_kernel(const float* __restrict__ Wq, const float* __restrict__ Wk,
                             const float* __restrict__ Wv, u16* __restrict__ wt) {
  int f = blockIdx.x * 256 + threadIdx.x;   // 3*65536 total
  int p = f >> 16, rem = f & 65535, n = rem >> 8, k = rem & 255;
  const float* W = (p == 0) ? Wq : ((p == 1) ? Wk : Wv);
  wt[f] = f2bf(W[k * 256 + n]);
}

// ---- QKV projection ----
__global__ __launch_bounds__(256) void proj_kernel(
    const float* __restrict__ x, const u16* __restrict__ wt,
    const float* __restrict__ bq, const float* __restrict__ bk, const float* __restrict__ bv,
    u16* __restrict__ qg, u16* __restrict__ kg, u16* __restrict__ vtg) {
  __shared__ u16 xs[64 * 256];
  const int tid = threadIdx.x;
  const int lane = tid & 63, w = tid >> 6, g = lane >> 4, l15 = lane & 15;
  const int tok0 = blockIdx.x * 64;

#pragma unroll
  for (int it = 0; it < 8; ++it) {
    int idx = it * 256 + tid;
    int r = idx >> 5, d0 = (idx & 31) << 3;
    const float* src = x + (size_t)(tok0 + r) * DD + d0;
    float4 a = *(const float4*)src;
    float4 bb = *(const float4*)(src + 4);
    v8s pk;
    pk[0] = (short)f2bf(a.x);  pk[1] = (short)f2bf(a.y);
    pk[2] = (short)f2bf(a.z);  pk[3] = (short)f2bf(a.w);
    pk[4] = (short)f2bf(bb.x); pk[5] = (short)f2bf(bb.y);
    pk[6] = (short)f2bf(bb.z); pk[7] = (short)f2bf(bb.w);
    *(v8s*)(xs + r * DD + (((d0 >> 3) ^ (r & 7)) << 3)) = pk;
  }
  __syncthreads();

  v8s af[4][8];
#pragma unroll
  for (int m = 0; m < 4; ++m) {
    const int row = 16 * m + l15;
#pragma unroll
    for (int c = 0; c < 8; ++c)
      af[m][c] = *(const v8s*)(xs + row * DD + ((((4 * c + g) ^ (row & 7))) << 3));
  }

  const float SCL = 0.0625f * 1.44269504088896f;  // 1/sqrt(D) * log2(e)
  for (int p = 0; p < 3; ++p) {
    const u16* wbase = wt + p * 65536;
    const float* bias = (p == 0) ? bq : ((p == 1) ? bk : bv);
    v4f acc[4][4];
    const v4f vzero = {0.f, 0.f, 0.f, 0.f};
#pragma unroll
    for (int m = 0; m < 4; ++m)
#pragma unroll
      for (int t = 0; t < 4; ++t) acc[m][t] = vzero;
#pragma unroll
    for (int t = 0; t < 4; ++t) {
      const int n = 64 * w + 16 * t + l15;
      const u16* wrow = wbase + n * 256;
#pragma unroll
      for (int c = 0; c < 8; ++c) {
        v8s bf = *(const v8s*)(wrow + 8 * g + 32 * c);
#pragma unroll
        for (int m = 0; m < 4; ++m)
          acc[m][t] = __builtin_amdgcn_mfma_f32_16x16x32_bf16(af[m][c], bf, acc[m][t], 0, 0, 0);
      }
    }
    if (p == 0) {
#pragma unroll
      for (int t = 0; t < 4; ++t) {
        int n = 64 * w + 16 * t + l15;
        float bb = bias[n];
#pragma unroll
        for (int m = 0; m < 4; ++m)
#pragma unroll
          for (int r = 0; r < 4; ++r)
            qg[(size_t)(tok0 + 16 * m + 4 * g + r) * DD + n] = f2bf((acc[m][t][r] + bb) * SCL);
      }
    } else if (p == 1) {
#pragma unroll
      for (int t = 0; t < 4; ++t) {
        int n = 64 * w + 16 * t + l15;
        float bb = bias[n];
#pragma unroll
        for (int m = 0; m < 4; ++m)
#pragma unroll
          for (int r = 0; r < 4; ++r)
            kg[(size_t)(tok0 + 16 * m + 4 * g + r) * DD + n] = f2bf(acc[m][t][r] + bb);
      }
    } else {
      const int b = tok0 >> 12;
      const int s0 = tok0 & 4095;
#pragma unroll
      for (int t = 0; t < 4; ++t) {
        int n = 64 * w + 16 * t + l15;
        float bb = bias[n];
#pragma unroll
        for (int m = 0; m < 4; ++m) {
          v4u pk;
#pragma unroll
          for (int r = 0; r < 4; ++r) pk[r] = f2bf(acc[m][t][r] + bb);
          *(v4u*)(vtg + (size_t)(b * DD + n) * SS + s0 + 16 * m + 4 * g) = pk;
        }
      }
    }
  }
}

// ---- flash attention: 256 thr / 4 waves x 32 q-rows, single-buffered K/V,
// ---- 80 KB LDS -> 2 blocks/CU (cross-block overlap replaces double-buffer) ----
#define STAGE(kt_)                                                               \
  {                                                                              \
    const int kt__ = (kt_);                                                      \
    _Pragma("unroll")                                                            \
    for (int it = 0; it < 8; ++it) {                                             \
      int idx = it * 256 + tid;                                                  \
      int r = idx >> 5, db = idx & 31;                                           \
      gload16(kbase + (size_t)(kt__ * 64 + r) * DD + ((db ^ (r & 7)) << 3),      \
              kb + idx * 8);                                                     \
    }                                                                            \
    _Pragma("unroll")                                                            \
    for (int it = 0; it < 8; ++it) {                                             \
      int idx = it * 256 + tid;                                                  \
      int d = idx >> 3, jb = idx & 7;                                            \
      gload16(vbase + (size_t)d * SS + kt__ * 64 + ((jb ^ (d & 7)) << 3),        \
              vt + idx * 8);                                                     \
    }                                                                            \
  }

__global__ __launch_bounds__(256) void attn_kernel(
    const u16* __restrict__ qg, const u16* __restrict__ kg, const u16* __restrict__ vtg,
    float* __restrict__ o0, float* __restrict__ opart, float* __restrict__ ml,
    int nsplit, int nblk) {
  extern __shared__ u16 sm[];
  u16* kb = sm;                 // [64*256]   swizzled K tile (also Q staging lo)
  u16* vt = sm + 16384;         // [256*64]   swizzled V^T tile (Q staging hi)
  u16* pb = sm + 32768;         // [4][32*64] per-wave P tiles

  const int bid = blockIdx.x;
  const int lg = (bid & 7) * (nblk >> 3) + (bid >> 3);  // XCD-contiguous logical id
  const int slice = lg >> 7;
  const int rem = lg & 127;
  const int b = rem >> 5;
  const int qt = rem & 31;
  const int NT = (SS / KVB) / nsplit;
  const int koff = slice * (SS / nsplit);

  const int tid = threadIdx.x;
  const int lane = tid & 63, w = tid >> 6, g = lane >> 4, l15 = lane & 15;

  const u16* qbase = qg + (size_t)(b * SS + qt * QB) * DD;
  const u16* kbase = kg + (size_t)(b * SS + koff) * DD;
  const u16* vbase = vtg + (size_t)b * DD * SS + koff;

  // stage Q tile (128x256 = 64 KB) into sm, hoist Q B-fragments to registers
#pragma unroll
  for (int it = 0; it < 16; ++it) {
    int idx = it * 256 + tid;
    int r = idx >> 5, db = idx & 31;
    gload16(qbase + (size_t)r * DD + ((db ^ (r & 7)) << 3), sm + idx * 8);
  }
  __syncthreads();
  v8s qf[2][8];
#pragma unroll
  for (int j = 0; j < 2; ++j) {
    const int row = 32 * w + 16 * j + l15;
#pragma unroll
    for (int c = 0; c < 8; ++c)
      qf[j][c] = *(const v8s*)(sm + row * DD + ((((4 * c + g) ^ (row & 7))) << 3));
  }
  __syncthreads();

  float mrow[2], lrow[2];
  v4f oacc[2][16];
  const v4f vzero = {0.f, 0.f, 0.f, 0.f};
#pragma unroll
  for (int j = 0; j < 2; ++j) { mrow[j] = -1e30f; lrow[j] = 0.f; }
#pragma unroll
  for (int m = 0; m < 2; ++m)
#pragma unroll
    for (int t = 0; t < 16; ++t) oacc[m][t] = vzero;

  for (int kt = 0; kt < NT; ++kt) {
    STAGE(kt);
    __syncthreads();                       // staging done; tile readable

    // S^T = K @ Q^T : lane holds S[key=16t+4g+r][qrow=32w+16j+l15]
    v4f sacc[4][2];
#pragma unroll
    for (int t = 0; t < 4; ++t)
#pragma unroll
      for (int j = 0; j < 2; ++j) sacc[t][j] = vzero;
#pragma unroll
    for (int c = 0; c < 8; ++c) {
#pragma unroll
      for (int t = 0; t < 4; ++t) {
        const int krow = 16 * t + l15;
        v8s kf = *(const v8s*)(kb + krow * DD + ((((4 * c + g) ^ (krow & 7))) << 3));
#pragma unroll
        for (int j = 0; j < 2; ++j)
          sacc[t][j] = __builtin_amdgcn_mfma_f32_16x16x32_bf16(kf, qf[j][c], sacc[t][j], 0, 0, 0);
      }
    }

    // online softmax in log2 domain; per-qrow stats are l15-local (2 shuffles)
    float tm[2];
#pragma unroll
    for (int j = 0; j < 2; ++j) {
      float a0 = fmaxf(fmaxf(sacc[0][j][0], sacc[0][j][1]), fmaxf(sacc[0][j][2], sacc[0][j][3]));
      float a1 = fmaxf(fmaxf(sacc[1][j][0], sacc[1][j][1]), fmaxf(sacc[1][j][2], sacc[1][j][3]));
      float a2 = fmaxf(fmaxf(sacc[2][j][0], sacc[2][j][1]), fmaxf(sacc[2][j][2], sacc[2][j][3]));
      float a3 = fmaxf(fmaxf(sacc[3][j][0], sacc[3][j][1]), fmaxf(sacc[3][j][2], sacc[3][j][3]));
      float t0 = fmaxf(fmaxf(a0, a1), fmaxf(a2, a3));
      t0 = fmaxf(t0, __shfl_xor(t0, 16));
      t0 = fmaxf(t0, __shfl_xor(t0, 32));
      tm[j] = t0;
    }
    // defer-rescale (T13): skip O-pass when max growth <= 11 (log2 units)
    const bool need = !__all((tm[0] - mrow[0] <= 11.0f) && (tm[1] - mrow[1] <= 11.0f));
    if (need) {
      float sc[2];
#pragma unroll
      for (int j = 0; j < 2; ++j) {
        float nm = fmaxf(mrow[j], tm[j]);
        sc[j] = exp2f(mrow[j] - nm);
        mrow[j] = nm;
        lrow[j] *= sc[j];
      }
#pragma unroll
      for (int m = 0; m < 2; ++m) {
#pragma unroll
        for (int r = 0; r < 4; ++r) {
          float s4 = __shfl(sc[m], (lane & 48) | (4 * g + r));
#pragma unroll
          for (int t = 0; t < 16; ++t) oacc[m][t][r] *= s4;
        }
      }
    }

    // P = exp2(S - m): bf16 pack, b64 writes to per-wave LDS tile [32][64]
    u16* pw = pb + w * 2048;
#pragma unroll
    for (int j = 0; j < 2; ++j) {
      const int prow = 16 * j + l15;
      float ls = 0.f;
#pragma unroll
      for (int t = 0; t < 4; ++t) {
        v4u pk;
#pragma unroll
        for (int r = 0; r < 4; ++r) {
          float e = exp2f(sacc[t][j][r] - mrow[j]);
          ls += e;
          pk[r] = f2bf(e);
        }
        *(v4u*)(pw + prow * 64 + (((2 * t + (g >> 1)) ^ (prow & 7)) << 3) + 4 * (g & 1)) = pk;
      }
      ls += __shfl_xor(ls, 16);
      ls += __shfl_xor(ls, 32);
      lrow[j] += ls;
    }

    // O += P @ V  (A = P from per-wave LDS, B = V^T tile)
#pragma unroll
    for (int kc2 = 0; kc2 < 2; ++kc2) {
      v8s pa[2];
#pragma unroll
      for (int m = 0; m < 2; ++m) {
        const int row = 16 * m + l15;
        pa[m] = *(const v8s*)(pw + row * 64 + ((((4 * kc2 + g) ^ (row & 7))) << 3));
      }
#pragma unroll
      for (int t = 0; t < 16; ++t) {
        const int d = 16 * t + l15;
        v8s bvv = *(const v8s*)(vt + d * 64 + ((((4 * kc2 + g) ^ (d & 7))) << 3));
#pragma unroll
        for (int m = 0; m < 2; ++m)
          oacc[m][t] = __builtin_amdgcn_mfma_f32_16x16x32_bf16(pa[m], bvv, oacc[m][t], 0, 0, 0);
      }
    }
    __syncthreads();                       // all waves done reading before next STAGE
  }

  // epilogue: write UNNORMALIZED partial O (f32) + per-row (m, l)
  float* ob = (slice == 0) ? o0 : (opart + (size_t)(slice - 1) * 4194304);
  const size_t rb = (size_t)b * SS + (size_t)qt * QB;
  if (g == 0) {
#pragma unroll
    for (int j = 0; j < 2; ++j) {
      const size_t rowg = rb + 32 * w + 16 * j + l15;
      float2 v2 = make_float2(mrow[j], lrow[j]);
      *(float2*)(ml + ((size_t)slice * 16384 + rowg) * 2) = v2;
    }
  }
#pragma unroll
  for (int m = 0; m < 2; ++m)
#pragma unroll
    for (int t = 0; t < 16; ++t)
#pragma unroll
      for (int r = 0; r < 4; ++r)
        ob[(rb + 32 * w + 16 * m + 4 * g + r) * DD + 16 * t + l15] = oacc[m][t][r];
}

// ---- merge kv-split partials (normalize when nsplit==1) ----
__global__ __launch_bounds__(256) void combine_kernel(
    float* __restrict__ out, const float* __restrict__ opart,
    const float* __restrict__ ml, int nsplit) {
  const int tid = threadIdx.x;
  const size_t row = (size_t)blockIdx.x * 4 + (tid >> 6);
  const int d = (tid & 63) * 4;
  float2 mls[4];
  float mm = -1e30f;
#pragma unroll
  for (int s = 0; s < 4; ++s) {
    if (s < nsplit) {
      mls[s] = *(const float2*)(ml + ((size_t)s * 16384 + row) * 2);
      mm = fmaxf(mm, mls[s].x);
    }
  }
  float l = 0.f;
  float4 acc = {0.f, 0.f, 0.f, 0.f};
#pragma unroll
  for (int s = 0; s < 4; ++s) {
    if (s < nsplit) {
      float a = exp2f(mls[s].x - mm);
      const float* src = (s == 0) ? (out + row * DD + d)
                                  : (opart + (size_t)(s - 1) * 4194304 + row * DD + d);
      float4 v = *(const float4*)src;
      l += a * mls[s].y;
      acc.x += a * v.x; acc.y += a * v.y; acc.z += a * v.z; acc.w += a * v.w;
    }
  }
  float inv = 1.0f / l;
  acc.x *= inv; acc.y *= inv; acc.z *= inv; acc.w *= inv;
  *(float4*)(out + row * DD + d) = acc;
}

extern "C" void kernel_launch(void* const* d_in, const int* in_sizes, int n_in,
                              void* d_out, int out_size, void* d_ws, size_t ws_size,
                              hipStream_t stream) {
  const float* x  = (const float*)d_in[0];
  const float* Wq = (const float*)d_in[1];
  const float* bq = (const float*)d_in[2];
  const float* Wk = (const float*)d_in[3];
  const float* bk = (const float*)d_in[4];
  const float* Wv = (const float*)d_in[5];
  const float* bv = (const float*)d_in[6];
  float* out = (float*)d_out;
  char* ws = (char*)d_ws;

  u16* wt    = (u16*)ws;                                  //   393,216 B
  u16* qg    = (u16*)(ws + 393216);                       // 8,388,608 B
  u16* kg    = (u16*)(ws + 393216 + 8388608);             // 8,388,608 B
  u16* vtg   = (u16*)(ws + 393216 + 2 * 8388608);         // 8,388,608 B
  float* ml  = (float*)(ws + 25559040);                   //   524,288 B (4 slices)
  float* op  = (float*)(ws + 26083328);                   // up to 3 x 16,777,216 B
  const size_t need4 = 26083328ull + 3ull * 16777216ull;  // ~76.4 MB
  const size_t need2 = 26083328ull + 1ull * 16777216ull;  // ~42.9 MB
  const int nsplit = (ws_size >= need4) ? 4 : ((ws_size >= need2) ? 2 : 1);
  const int nblk = 128 * nsplit;

  (void)hipFuncSetAttribute((const void*)attn_kernel,
                            hipFuncAttributeMaxDynamicSharedMemorySize, 81920);

  wcast_kernel<<<dim3(768), dim3(256), 0, stream>>>(Wq, Wk, Wv, wt);
  proj_kernel<<<dim3(256), dim3(256), 0, stream>>>(x, wt, bq, bk, bv, qg, kg, vtg);
  attn_kernel<<<dim3(nblk), dim3(256), 81920, stream>>>(qg, kg, vtg, out, op, ml, nsplit, nblk);
  combine_kernel<<<dim3(4096), dim3(256), 0, stream>>>(out, op, ml, nsplit);
}